// Round 5
// baseline (8776.483 us; speedup 1.0000x reference)
//
#include <hip/hip_runtime.h>
#include <cstddef>
#include <cstdint>

#define Bn 32
#define Sn 512
#define Hn 512
#define Rn (Bn*Sn)
#define NLAYER 4
constexpr size_t NHe = (size_t)Rn * Hn;   // 8,388,608 elements per (B,S,H) tensor

typedef __attribute__((ext_vector_type(8))) short bf16x8;
typedef __attribute__((ext_vector_type(4))) float f32x4;
#define AS1 __attribute__((address_space(1)))
#define AS3 __attribute__((address_space(3)))

__device__ __forceinline__ void gload16(const void* g, void* l) {
  __builtin_amdgcn_global_load_lds((const AS1 void*)g, (AS3 void*)l, 16, 0, 0);
}

__device__ __forceinline__ float sigf(float x) { return 1.f / (1.f + __expf(-x)); }
// round-to-nearest-even f32 -> bf16 (raw uint16)
__device__ __forceinline__ unsigned short bfh(float x) {
  unsigned u = __float_as_uint(x);
  u += 0x7fffu + ((u >> 16) & 1u);
  return (unsigned short)(u >> 16);
}

// ---------------- init: h = init_h*m, c = init_c*m ----------------
__global__ void k_init(const float* __restrict__ ih, const float* __restrict__ ic,
                       const int* __restrict__ mask,
                       float* __restrict__ h, float* __restrict__ c) {
  size_t i = (size_t)blockIdx.x * blockDim.x + threadIdx.x;  // NHe/4
  size_t n = i >> 7;
  float m = (float)mask[n];
  float4 b = ((const float4*)ih)[i];
  float4 d = ((const float4*)ic)[i];
  b.x *= m; b.y *= m; b.z *= m; b.w *= m;
  d.x *= m; d.y *= m; d.z *= m; d.w *= m;
  ((float4*)h)[i] = b; ((float4*)c)[i] = d;
}

// ---------------- zero pn/pd ----------------
__global__ void k_zero(float* __restrict__ p) {
  ((float4*)p)[blockIdx.x * 256 + threadIdx.x] = make_float4(0.f, 0.f, 0.f, 0.f);
}

// ---------------- mean over s, two-stage ----------------
__global__ void k_mean1a(const float* __restrict__ x, float* __restrict__ part) {
  int b = blockIdx.x >> 3, sc = blockIdx.x & 7;
  int k = threadIdx.x;
  const float* px = x + ((size_t)b * Sn + sc * 64) * Hn;
  float s0 = 0.f, s1 = 0.f;
#pragma unroll 8
  for (int t = 0; t < 64; ++t) { s0 += px[(size_t)t * Hn + k]; s1 += px[(size_t)t * Hn + k + 256]; }
  part[(size_t)blockIdx.x * Hn + k] = s0;
  part[(size_t)blockIdx.x * Hn + k + 256] = s1;
}
__global__ void k_mean1b(const float* __restrict__ part, float* __restrict__ o) {
  int idx = blockIdx.x * blockDim.x + threadIdx.x;  // B*H
  int b = idx >> 9, k = idx & 511;
  float s = 0.f;
#pragma unroll
  for (int sc = 0; sc < 8; ++sc) s += part[(size_t)(b * 8 + sc) * Hn + k];
  o[idx] = s * (1.f / Sn);
}

// ---------------- small gates: gd, go, gfA ----------------
__global__ void k_gates_small(const float* __restrict__ dh, const float* __restrict__ comb,
                              const float* __restrict__ gW, const float* __restrict__ gb,
                              float* __restrict__ gd, float* __restrict__ go,
                              float* __restrict__ gfA) {
  int idx = blockIdx.x * blockDim.x + threadIdx.x;  // B*H
  int b = idx >> 9, k = idx & 511;
  const float* gW0 = gW;
  const float* gW1 = gW + 1 * Hn * Hn;
  const float* gW2 = gW + 2 * Hn * Hn;
  const float* gW3 = gW + 3 * Hn * Hn;
  const float* gW4 = gW + 4 * Hn * Hn;
  const float* dhb = dh + b * Hn;
  const float* cbp = comb + b * Hn;
  float s0 = 0.f, s1 = 0.f, s2 = 0.f, s3 = 0.f, s4 = 0.f;
#pragma unroll 4
  for (int j = 0; j < Hn; ++j) {
    float a = dhb[j], c2 = cbp[j];
    s0 += a * gW0[j * Hn + k];
    s1 += c2 * gW1[j * Hn + k];
    s2 += a * gW2[j * Hn + k];
    s3 += c2 * gW3[j * Hn + k];
    s4 += a * gW4[j * Hn + k];
  }
  gd[idx] = sigf(s0 + s1 + gb[k]);
  go[idx] = sigf(s2 + s3 + gb[Hn + k]);
  gfA[idx] = s4 + gb[2 * Hn + k];
}

// ---------------- dWd[g,b,k] = dummy_h[b,:] @ Wd[g,:,k] ----------------
__global__ void k_dWd(const float* __restrict__ dh, const float* __restrict__ Wd,
                      float* __restrict__ dWd) {
  int idx = blockIdx.x * blockDim.x + threadIdx.x;  // 8*B*H
  int k = idx & 511; int bg = idx >> 9; int b = bg & 31; int g = bg >> 5;
  const float* w = Wd + (size_t)g * Hn * Hn;
  const float* dhb = dh + b * Hn;
  float s = 0.f;
#pragma unroll 4
  for (int j = 0; j < Hn; ++j) s += dhb[j] * w[j * Hn + k];
  dWd[idx] = s;
}

// ---------------- A-plane prep: h -> hhat(hi,lo), hb(hi), ha(hi), frag-ordered ----------------
// plane unit U = rgG*1024 + kcT*64 + quad*16 + l15  (one int4 = 8 shorts)
//   element: row = rgG*16 + l15, k = kcT*32 + quad*8 + j
__global__ void k_prep(const float* __restrict__ h, short* __restrict__ hH,
                       short* __restrict__ hL, short* __restrict__ hb,
                       short* __restrict__ ha) {
  int U = blockIdx.x * 256 + threadIdx.x;   // 1,048,576 units
  int rgG = U >> 10; int w = U & 1023;
  int kcT = w >> 6; int quad = (w >> 4) & 3; int l15 = w & 15;
  int row = rgG * 16 + l15; int s = row & (Sn - 1);
  int k0 = kcT * 32 + quad * 8;
  const float* hp = h + (size_t)row * Hn + k0;
  size_t o = (size_t)U * 8;
#pragma unroll
  for (int j = 0; j < 8; ++j) {
    float v = hp[j];
    unsigned short hh = bfh(v);
    hH[o + j] = (short)hh;
    hL[o + j] = (short)bfh(v - __uint_as_float((unsigned)hh << 16));
    float b2 = (s >= 1 ? hp[j - Hn] : 0.f) + (s >= 2 ? hp[j - 2 * Hn] : 0.f);
    float a2 = (s <= Sn - 2 ? hp[j + Hn] : 0.f) + (s <= Sn - 3 ? hp[j + 2 * Hn] : 0.f);
    hb[o + j] = (short)bfh(b2);
    ha[o + j] = (short)bfh(a2);
  }
}

// ---------------- weight pre-swizzle (5 terms x 8 groups) ----------------
// superblock sb = (t*16 + nT)*16 + kcT : 8192 shorts; interior (((g*2+ni)*4+quad)*16+l15)*8+j
//   n = nT*32 + ni*16 + l15, k = kcT*32 + quad*8 + j
__global__ void k_convw(const float* __restrict__ Wx, const float* __restrict__ Wh,
                        const float* __restrict__ Wsm, const float* __restrict__ Wi,
                        short* __restrict__ Bhat) {
  int kcT = blockIdx.x, nT = blockIdx.y, tg = blockIdx.z;  // 16,16,40
  int t = tg >> 3, g = tg & 7;
  const float* base;
  if (t == 0)      base = Wx  + (size_t)g * 262144;
  else if (t == 1) base = Wh  + (size_t)g * 524288;
  else if (t == 2) base = Wh  + (size_t)g * 524288 + 262144;
  else if (t == 3) base = Wsm + (size_t)g * 262144;
  else             base = Wi  + (size_t)g * 262144;
  size_t sbase = ((size_t)(t * 16 + nT) * 16 + kcT) * 8192 + (size_t)g * 1024;
  int lane = threadIdx.x;  // 64
  for (int cch = lane; cch < 128; cch += 64) {
    int ni = cch >> 6, quad = (cch >> 4) & 3, l15 = cch & 15;
    int n = nT * 32 + ni * 16 + l15;
    int k0 = kcT * 32 + quad * 8;
#pragma unroll
    for (int j = 0; j < 8; ++j)
      Bhat[sbase + (size_t)cch * 8 + j] = (short)bfh(base[(size_t)(k0 + j) * Hn + n]);
  }
}

// gWhf swizzle: Ghat[(nT*16+kcT)*1024 + (ni*64+quad*16+l15)*8 + j]
__global__ void k_convG(const float* __restrict__ gW5, short* __restrict__ Ghat) {
  int kcT = blockIdx.x, nT = blockIdx.y;  // 16,16
  int lane = threadIdx.x;
  size_t sbase = ((size_t)nT * 16 + kcT) * 1024;
  for (int cch = lane; cch < 128; cch += 64) {
    int ni = cch >> 6, quad = (cch >> 4) & 3, l15 = cch & 15;
    int n = nT * 32 + ni * 16 + l15;
    int k0 = kcT * 32 + quad * 8;
#pragma unroll
    for (int j = 0; j < 8; ++j)
      Ghat[sbase + (size_t)cch * 8 + j] = (short)bfh(gW5[(size_t)(k0 + j) * Hn + n]);
  }
}

// ---------------- fused: G-tile = h @ gWhf (MFMA) -> e=exp(sig(G+gfa))*mask ->
//                  partial sums atomically into pn (Σ e·c) and pd (Σ e) ----------------
__global__ __launch_bounds__(256, 2) void k_gemmG(const short* __restrict__ hH,
                                                  const short* __restrict__ hL,
                                                  const short* __restrict__ Ghat,
                                                  const float* __restrict__ gfA,
                                                  const float* __restrict__ c,
                                                  const int* __restrict__ mask,
                                                  float* __restrict__ pn,
                                                  float* __restrict__ pd) {
  __shared__ short AsH[4096], AsL[4096], Bs[1024];
  __shared__ float redN[4][32], redD[4][32];
  const int tid = threadIdx.x;
  const int id = blockIdx.x;          // 2048
  const int xcd = id & 7;
  const int loc = id >> 3;            // 0..255
  const int mb = xcd * 16 + (loc & 15);
  const int nT = loc >> 4;
  const int m0 = mb * 128;
  const int n0 = nT * 32;
  const int bb = m0 >> 9;
  const int lane = tid & 63, wid = tid >> 6;
  const int quad = lane >> 4, l15 = lane & 15;

  f32x4 acc[2][2];
#pragma unroll
  for (int mi = 0; mi < 2; ++mi)
#pragma unroll
    for (int ni = 0; ni < 2; ++ni) acc[mi][ni] = (f32x4){0.f, 0.f, 0.f, 0.f};

  const int afo0 = (((wid * 2 + 0) * 4 + quad) * 16 + l15) * 8;
  const int afo1 = (((wid * 2 + 1) * 4 + quad) * 16 + l15) * 8;

#pragma unroll 1
  for (int kcT = 0; kcT < 16; ++kcT) {
    __syncthreads();
    if (tid < 128)
      gload16((const int4*)Ghat + ((size_t)(nT * 16 + kcT)) * 128 + tid,
              &Bs[(tid & 64) * 8]);
#pragma unroll
    for (int uu = 0; uu < 2; ++uu) {
      int u = tid + uu * 256;
      size_t su = ((size_t)(mb * 8 + (u >> 6))) * 1024 + kcT * 64 + (u & 63);
      gload16((const int4*)hH + su, &AsH[(u & ~63) * 8]);
      gload16((const int4*)hL + su, &AsL[(u & ~63) * 8]);
    }
    __syncthreads();
    bf16x8 ah0 = *(const bf16x8*)&AsH[afo0];
    bf16x8 ah1 = *(const bf16x8*)&AsH[afo1];
    bf16x8 al0 = *(const bf16x8*)&AsL[afo0];
    bf16x8 al1 = *(const bf16x8*)&AsL[afo1];
#pragma unroll
    for (int ni = 0; ni < 2; ++ni) {
      bf16x8 b = *(const bf16x8*)&Bs[((ni * 4 + quad) * 16 + l15) * 8];
      acc[0][ni] = __builtin_amdgcn_mfma_f32_16x16x32_bf16(ah0, b, acc[0][ni], 0, 0, 0);
      acc[0][ni] = __builtin_amdgcn_mfma_f32_16x16x32_bf16(al0, b, acc[0][ni], 0, 0, 0);
      acc[1][ni] = __builtin_amdgcn_mfma_f32_16x16x32_bf16(ah1, b, acc[1][ni], 0, 0, 0);
      acc[1][ni] = __builtin_amdgcn_mfma_f32_16x16x32_bf16(al1, b, acc[1][ni], 0, 0, 0);
    }
  }

  // fused dummy-softmax partial reduction over this block's 128 rows
  float gfa[2];
#pragma unroll
  for (int ni = 0; ni < 2; ++ni) gfa[ni] = gfA[bb * Hn + n0 + ni * 16 + l15];
  float sn[2] = {0.f, 0.f}, sd[2] = {0.f, 0.f};
#pragma unroll
  for (int mi = 0; mi < 2; ++mi)
#pragma unroll
    for (int r = 0; r < 4; ++r) {
      int row = m0 + wid * 32 + mi * 16 + quad * 4 + r;
      float mf = (float)mask[row];
#pragma unroll
      for (int ni = 0; ni < 2; ++ni) {
        float e = __expf(sigf(acc[mi][ni][r] + gfa[ni])) * mf;
        sn[ni] += e * c[(size_t)row * Hn + n0 + ni * 16 + l15];
        sd[ni] += e;
      }
    }
#pragma unroll
  for (int ni = 0; ni < 2; ++ni) {
    sn[ni] += __shfl_xor(sn[ni], 16); sn[ni] += __shfl_xor(sn[ni], 32);
    sd[ni] += __shfl_xor(sd[ni], 16); sd[ni] += __shfl_xor(sd[ni], 32);
  }
  if (quad == 0) {
#pragma unroll
    for (int ni = 0; ni < 2; ++ni) {
      redN[wid][ni * 16 + l15] = sn[ni];
      redD[wid][ni * 16 + l15] = sd[ni];
    }
  }
  __syncthreads();
  if (tid < 32) {
    float a = 0.f, b = 0.f;
#pragma unroll
    for (int w = 0; w < 4; ++w) { a += redN[w][tid]; b += redD[w][tid]; }
    atomicAdd(&pn[bb * Hn + n0 + tid], a);
    atomicAdd(&pd[bb * Hn + n0 + tid], b);
  }
}

// ---------------- dummy gate finalize ----------------
__global__ void k_dummy2(const float* __restrict__ pn, const float* __restrict__ pd,
                         const float* __restrict__ gd, const float* __restrict__ go,
                         const float* __restrict__ dc,
                         float* __restrict__ dh2, float* __restrict__ dc2) {
  int idx = blockIdx.x * blockDim.x + threadIdx.x;  // B*H
  float ed = __expf(gd[idx]);
  float num = ed * dc[idx] + pn[idx];
  float den = ed + pd[idx];
  float d = num / den;
  dc2[idx] = d;
  dh2[idx] = go[idx] * tanhf(d);
}

// ---------------- mega GEMM (MFMA, pre-split A planes) + fused gate epilogue ----------------
// BM=128, BN=32, BK=32; 256 threads = 4 waves; wave w owns rows [w*32,w*32+32)
__global__ __launch_bounds__(256, 2) void k_mega(
    const float* __restrict__ c, const float* __restrict__ word,
    const short* __restrict__ hH, const short* __restrict__ hL,
    const short* __restrict__ hbh, const short* __restrict__ hah,
    const short* __restrict__ Bhat,
    const int* __restrict__ pos, const int* __restrict__ mask,
    const float* __restrict__ dc, const float* __restrict__ dWd,
    const float* __restrict__ bias,
    float* __restrict__ hout, float* __restrict__ cout) {
  __shared__ short AsH[4096], AsL[4096], Bs[8192];

  const int tid = threadIdx.x;
  const int id = blockIdx.x;        // 2048
  const int xcd = id & 7;
  const int loc = id >> 3;          // 0..255
  const int nT = xcd * 2 + (loc >> 7);
  const int mb = loc & 127;
  const int m0 = mb * 128;
  const int n0 = nT * 32;
  const int bb = m0 >> 9;
  const int lane = tid & 63, wid = tid >> 6;
  const int quad = lane >> 4, l15 = lane & 15;

  f32x4 acc[8][2][2];
#pragma unroll
  for (int g = 0; g < 8; ++g)
#pragma unroll
    for (int mi = 0; mi < 2; ++mi)
#pragma unroll
      for (int ni = 0; ni < 2; ++ni) acc[g][mi][ni] = (f32x4){0.f, 0.f, 0.f, 0.f};

  const int afo0 = (((wid * 2 + 0) * 4 + quad) * 16 + l15) * 8;
  const int afo1 = (((wid * 2 + 1) * 4 + quad) * 16 + l15) * 8;

  // per-staged-unit coords (units u=tid and u=tid+256): row, quad-within-row
  const int urow0 = m0 + ((tid >> 6) << 4) + (tid & 15);
  const int urow1 = m0 + (((tid + 256) >> 6) << 4) + (tid & 15);
  const int uq0 = (tid >> 4) & 3;
  const int uq1 = ((tid + 256) >> 4) & 3;
  const int gp0 = pos[urow0];
  const int gp1 = pos[urow1];
  const float wm0 = (float)mask[urow0];
  const float wm1 = (float)mask[urow1];
  const float4* wrow0 = (const float4*)(word + (size_t)urow0 * Hn);
  const float4* wrow1 = (const float4*)(word + (size_t)urow1 * Hn);

#pragma unroll 1
  for (int t = 0; t < 5; ++t) {
    const short* pH = (t == 1) ? hbh : ((t == 2) ? hah : hH);
    const bool two = (t == 0) || (t == 3) || (t == 4);

#pragma unroll 1
    for (int kcT = 0; kcT < 16; ++kcT) {
      __syncthreads();
      // ---- stage B: flat superblock (8 groups x 32n x 32k), 4x global_load_lds ----
      const int4* bsrc = (const int4*)Bhat + ((size_t)((t * 16 + nT) * 16 + kcT)) * 1024;
#pragma unroll
      for (int q = 0; q < 4; ++q)
        gload16(bsrc + q * 256 + tid, &Bs[(q * 256 + (tid & 192)) * 8]);
      // ---- stage A ----
      if (t < 3) {
#pragma unroll
        for (int uu = 0; uu < 2; ++uu) {
          int u = tid + uu * 256;
          size_t su = ((size_t)(mb * 8 + (u >> 6))) * 1024 + kcT * 64 + (u & 63);
          gload16((const int4*)pH + su, &AsH[(u & ~63) * 8]);
          if (t == 0) gload16((const int4*)hL + su, &AsL[(u & ~63) * 8]);
        }
      } else if (t == 3) {
        int4 z4 = {0, 0, 0, 0};
        if (gp0) {
          int rT = bb * Sn + gp0 - 1;
          size_t su = ((size_t)(rT >> 4)) * 1024 + kcT * 64 + uq0 * 16 + (rT & 15);
          ((int4*)AsH)[tid] = ((const int4*)hH)[su];
          ((int4*)AsL)[tid] = ((const int4*)hL)[su];
        } else { ((int4*)AsH)[tid] = z4; ((int4*)AsL)[tid] = z4; }
        if (gp1) {
          int rT = bb * Sn + gp1 - 1;
          size_t su = ((size_t)(rT >> 4)) * 1024 + kcT * 64 + uq1 * 16 + (rT & 15);
          ((int4*)AsH)[tid + 256] = ((const int4*)hH)[su];
          ((int4*)AsL)[tid + 256] = ((const int4*)hL)[su];
        } else { ((int4*)AsH)[tid + 256] = z4; ((int4*)AsL)[tid + 256] = z4; }
      } else {
        // t == 4: emb = word*mask converted on the fly (hi/lo)
#pragma unroll
        for (int uu = 0; uu < 2; ++uu) {
          int u = tid + uu * 256;
          int kq = (kcT * 32 + (uu ? uq1 : uq0) * 8) >> 2;
          const float4* wr = uu ? wrow1 : wrow0;
          float wm = uu ? wm1 : wm0;
          float4 va = wr[kq], vb = wr[kq + 1];
          float v[8] = {va.x, va.y, va.z, va.w, vb.x, vb.y, vb.z, vb.w};
          bf16x8 hi, lo;
#pragma unroll
          for (int j = 0; j < 8; ++j) {
            float x = v[j] * wm;
            unsigned short hh = bfh(x);
            hi[j] = (short)hh;
            lo[j] = (short)bfh(x - __uint_as_float((unsigned)hh << 16));
          }
          *(bf16x8*)&AsH[(size_t)u * 8] = hi;
          *(bf16x8*)&AsL[(size_t)u * 8] = lo;
        }
      }
      __syncthreads();
      // ---- MFMA ----
      bf16x8 ah0 = *(const bf16x8*)&AsH[afo0];
      bf16x8 ah1 = *(const bf16x8*)&AsH[afo1];
      if (two) {
        bf16x8 al0 = *(const bf16x8*)&AsL[afo0];
        bf16x8 al1 = *(const bf16x8*)&AsL[afo1];
#pragma unroll
        for (int g = 0; g < 8; ++g)
#pragma unroll
          for (int ni = 0; ni < 2; ++ni) {
            bf16x8 b = *(const bf16x8*)&Bs[(((g * 2 + ni) * 4 + quad) * 16 + l15) * 8];
            acc[g][0][ni] = __builtin_amdgcn_mfma_f32_16x16x32_bf16(ah0, b, acc[g][0][ni], 0, 0, 0);
            acc[g][0][ni] = __builtin_amdgcn_mfma_f32_16x16x32_bf16(al0, b, acc[g][0][ni], 0, 0, 0);
            acc[g][1][ni] = __builtin_amdgcn_mfma_f32_16x16x32_bf16(ah1, b, acc[g][1][ni], 0, 0, 0);
            acc[g][1][ni] = __builtin_amdgcn_mfma_f32_16x16x32_bf16(al1, b, acc[g][1][ni], 0, 0, 0);
          }
      } else {
#pragma unroll
        for (int g = 0; g < 8; ++g)
#pragma unroll
          for (int ni = 0; ni < 2; ++ni) {
            bf16x8 b = *(const bf16x8*)&Bs[(((g * 2 + ni) * 4 + quad) * 16 + l15) * 8];
            acc[g][0][ni] = __builtin_amdgcn_mfma_f32_16x16x32_bf16(ah0, b, acc[g][0][ni], 0, 0, 0);
            acc[g][1][ni] = __builtin_amdgcn_mfma_f32_16x16x32_bf16(ah1, b, acc[g][1][ni], 0, 0, 0);
          }
      }
    }
  }

  // ---- fused epilogue (round-3 verified) ----
  float biasr[8][2], dwdr[8][2], tdcv[2];
#pragma unroll
  for (int ni = 0; ni < 2; ++ni) {
    int col = n0 + ni * 16 + l15;
    tdcv[ni] = dc[bb * Hn + col];
#pragma unroll
    for (int g = 0; g < 8; ++g) {
      biasr[g][ni] = bias[g * Hn + col];
      dwdr[g][ni] = dWd[((size_t)g * Bn + bb) * Hn + col];
    }
  }

#pragma unroll
  for (int mi = 0; mi < 2; ++mi) {
#pragma unroll
    for (int r = 0; r < 4; ++r) {
      const int row = m0 + wid * 32 + mi * 16 + quad * 4 + r;
      const int srow = row & (Sn - 1);
      const float mf = (float)mask[row];
      const int pp = pos[row];
      const size_t rb = (size_t)row * Hn;
#pragma unroll
      for (int ni = 0; ni < 2; ++ni) {
        const int col = n0 + ni * 16 + l15;
        float cf = c[rb + col];
        float cb = 0.f, ca = 0.f;
        if (srow >= 1) cb = c[rb - Hn + col];
        if (srow >= 2) cb += c[rb - 2 * Hn + col];
        if (srow <= Sn - 2) ca = c[rb + Hn + col];
        if (srow <= Sn - 3) ca += c[rb + 2 * Hn + col];
        float sw = pp ? c[((size_t)(bb * Sn + pp - 1)) * Hn + col] : 0.f;
        float z[8];
#pragma unroll
        for (int g = 0; g < 8; ++g)
          z[g] = acc[g][mi][ni][r] + biasr[g][ni] + dwdr[g][ni];
        float e0 = __expf(sigf(z[0]));
        float e1 = __expf(sigf(z[1]));
        float e2 = __expf(sigf(z[2]));
        float e3 = __expf(sigf(z[3]));
        float e4 = __expf(sigf(z[4]));
        float e5 = __expf(sigf(z[5]));
        float inv = 1.f / (e0 + e1 + e2 + e3 + e4 + e5);
        float o = sigf(z[6]);
        float u = tanhf(z[7]);
        float cn = inv * (e0 * cb + e1 * ca + e2 * cf + e3 * tdcv[ni] + e4 * sw + e5 * u);
        cout[rb + col] = cn * mf;
        hout[rb + col] = o * tanhf(cn) * mf;
      }
    }
  }
}

extern "C" void kernel_launch(void* const* d_in, const int* in_sizes, int n_in,
                              void* d_out, int out_size, void* d_ws, size_t ws_size,
                              hipStream_t stream) {
  (void)in_sizes; (void)n_in; (void)out_size; (void)ws_size;
  const float* word   = (const float*)d_in[0];
  const float* init_h = (const float*)d_in[1];
  const float* init_c = (const float*)d_in[2];
  const float* Wx     = (const float*)d_in[3];
  const float* Wh     = (const float*)d_in[4];
  const float* Wi     = (const float*)d_in[5];
  const float* Wdm    = (const float*)d_in[6];
  const float* Wsm    = (const float*)d_in[7];
  const float* bias   = (const float*)d_in[8];
  const float* gW     = (const float*)d_in[9];
  const float* gb     = (const float*)d_in[10];
  const int*   pos    = (const int*)d_in[11];
  const int*   mask   = (const int*)d_in[12];

  float* ws = (float*)d_ws;
  size_t off = 0;
  auto alloc = [&](size_t nel) { float* p = ws + off; off += nel; return p; };
  float* hA   = alloc(NHe);                             // 33.5 MB
  float* cA   = alloc(NHe);
  float* cB   = alloc(NHe);
  short* Bhat = (short*)alloc(5 * 8 * 512 * 512 / 2);   // 21 MB
  short* Ghat = (short*)alloc(512 * 512 / 2);           // 0.5 MB
  short* hH   = (short*)alloc(NHe / 2);                 // 16.8 MB each
  short* hL   = (short*)alloc(NHe / 2);
  short* hbh  = (short*)alloc(NHe / 2);
  short* hah  = (short*)alloc(NHe / 2);
  float* pc   = alloc(256 * Hn);
  float* pn   = alloc(Bn * Hn);
  float* pd   = alloc(Bn * Hn);
  float* dh   = alloc(Bn * Hn);
  float* dc   = alloc(Bn * Hn);
  float* dh2  = alloc(Bn * Hn);
  float* dc2  = alloc(Bn * Hn);
  float* comb = alloc(Bn * Hn);
  float* gd   = alloc(Bn * Hn);
  float* go   = alloc(Bn * Hn);
  float* gfA  = alloc(Bn * Hn);
  float* dWd  = alloc(8 * Bn * Hn);
  // total = 47,742,976 floats = 191.0 MB (round-3-verified budget)

  dim3 blk(256);
  int g4 = (int)(NHe / 4 / 256);          // 8192
  int gbh = (Bn * Hn) / 256;              // 64

  k_convw<<<dim3(16, 16, 40), dim3(64), 0, stream>>>(Wx, Wh, Wsm, Wi, Bhat);
  k_convG<<<dim3(16, 16), dim3(64), 0, stream>>>(gW + (size_t)5 * Hn * Hn, Ghat);
  k_init<<<g4, blk, 0, stream>>>(init_h, init_c, mask, hA, cA);
  k_mean1a<<<256, blk, 0, stream>>>(hA, pc);
  k_mean1b<<<gbh, blk, 0, stream>>>(pc, dh);
  k_mean1a<<<256, blk, 0, stream>>>(cA, pc);
  k_mean1b<<<gbh, blk, 0, stream>>>(pc, dc);

  float* ccur = cA; float* cnxt = cB;
  for (int l = 0; l < NLAYER; ++l) {
    k_mean1a<<<256, blk, 0, stream>>>(hA, pc);
    k_mean1b<<<gbh, blk, 0, stream>>>(pc, comb);
    k_gates_small<<<gbh, blk, 0, stream>>>(dh, comb, gW, gb, gd, go, gfA);
    k_dWd<<<(8 * Bn * Hn) / 256, blk, 0, stream>>>(dh, Wdm, dWd);
    k_prep<<<4096, blk, 0, stream>>>(hA, hH, hL, hbh, hah);
    k_zero<<<32, blk, 0, stream>>>(pn);                 // zeroes pn+pd (adjacent)
    k_gemmG<<<2048, blk, 0, stream>>>(hH, hL, Ghat, gfA, ccur, mask, pn, pd);
    k_dummy2<<<gbh, blk, 0, stream>>>(pn, pd, gd, go, dc, dh2, dc2);

    float* hout = (l == NLAYER - 1) ? (float*)d_out : hA;
    k_mega<<<2048, blk, 0, stream>>>(
        ccur, word, hH, hL, hbh, hah, Bhat, pos, mask, dc, dWd, bias, hout, cnxt);

    float* t1;
    t1 = ccur; ccur = cnxt; cnxt = t1;
    t1 = dh; dh = dh2; dh2 = t1;
    t1 = dc; dc = dc2; dc2 = t1;
  }
}